// Round 3
// baseline (104.963 us; speedup 1.0000x reference)
//
#include <hip/hip_runtime.h>
#include <hip/hip_bf16.h>

#define SLEN 8192
#define EDIM 1024

// ---------------- helpers ----------------

__device__ inline float waveReduceSum64(float v) {
#pragma unroll
    for (int off = 32; off; off >>= 1) v += __shfl_xor(v, off);
    return v;
}

__device__ inline float blockSum1024(float v, float* lds) {
    v = waveReduceSum64(v);
    int w = threadIdx.x >> 6, ln = threadIdx.x & 63;
    __syncthreads();
    if (ln == 0) lds[w] = v;
    __syncthreads();
    float s = (ln < 16) ? lds[ln] : 0.f;
#pragma unroll
    for (int off = 8; off; off >>= 1) s += __shfl_xor(s, off);
    s = __shfl(s, 0);
    return s;
}

// ---------------- QKV GEMV (split-K partials) ----------------
// grid (12, 16), block 256
__global__ __launch_bounds__(256) void qkv_partial(
    const float* __restrict__ Wq, const float* __restrict__ Wk,
    const float* __restrict__ Wv, const float* __restrict__ x,
    float* __restrict__ part) {
    int cg = blockIdx.x;
    int m = cg >> 2;
    const float* W = (m == 0) ? Wq : ((m == 1) ? Wk : Wv);
    int col = (cg & 3) * 256 + threadIdx.x;
    int r0 = blockIdx.y * 64;
    float acc = 0.f;
#pragma unroll 8
    for (int r = 0; r < 64; ++r)
        acc = fmaf(x[r0 + r], W[(r0 + r) * EDIM + col], acc);
    part[((size_t)m * 16 + blockIdx.y) * EDIM + col] = acc;
}

// grid 3, block 1024
__global__ __launch_bounds__(1024) void qkv_combine(
    const float* __restrict__ part,
    const float* __restrict__ bq, const float* __restrict__ bk,
    const float* __restrict__ bv,
    float* __restrict__ qs, float* __restrict__ ki, float* __restrict__ vi) {
    int m = blockIdx.x, t = threadIdx.x;
    float v = 0.f;
#pragma unroll
    for (int sl = 0; sl < 16; ++sl) v += part[((size_t)m * 16 + sl) * EDIM + t];
    if (m == 0) qs[t] = (v + bq[t]) * 0.125f;   // pre-scale q by 1/sqrt(64)
    else if (m == 1) ki[t] = v + bk[t];
    else vi[t] = v + bv[t];
}

// ---------------- fused cache-shift + flash attention (partials) ----------------
// block 256 (4 waves). Each wave handles PPW consecutive positions.
template<int PPW>
__global__ __launch_bounds__(256) void attn_main(
    const float* __restrict__ cache,   // [2, S, 1024]
    const float* __restrict__ qs,      // q/8 [1024]
    const float* __restrict__ ki, const float* __restrict__ vi,
    float* __restrict__ nv, float* __restrict__ nk,
    float* __restrict__ pm, float* __restrict__ pl, float* __restrict__ pacc) {
    int tid = threadIdx.x;
    int wid = blockIdx.x * 4 + (tid >> 6);
    int ld = tid & 63;

    float4 q4[4];
#pragma unroll
    for (int it = 0; it < 4; ++it)
        q4[it] = *(const float4*)(qs + it * 256 + ld * 4);

    float m4[4], l4[4];
    float4 a4[4];
#pragma unroll
    for (int it = 0; it < 4; ++it) {
        m4[it] = -1e30f; l4[it] = 0.f;
        a4[it] = make_float4(0.f, 0.f, 0.f, 0.f);
    }

    int s0 = wid * PPW;
#pragma unroll 2
    for (int p = 0; p < PPW; ++p) {
        int s = s0 + p;
        const float* vsrc;
        const float* ksrc;
        if (s < SLEN - 1) {
            vsrc = cache + (size_t)(s + 1) * EDIM;
            ksrc = cache + (size_t)SLEN * EDIM + (size_t)(s + 1) * EDIM;
        } else {
            vsrc = vi; ksrc = ki;
        }
        float4 vv[4], kv[4];
        float sc[4];
        bool nz = false;
#pragma unroll
        for (int it = 0; it < 4; ++it) {
            vv[it] = *(const float4*)(vsrc + it * 256 + ld * 4);
            kv[it] = *(const float4*)(ksrc + it * 256 + ld * 4);
        }
#pragma unroll
        for (int it = 0; it < 4; ++it) {
            *(float4*)(nv + (size_t)s * EDIM + it * 256 + ld * 4) = vv[it];
            *(float4*)(nk + (size_t)s * EDIM + it * 256 + ld * 4) = kv[it];
            nz = nz || (vv[it].x != 0.f) || (vv[it].y != 0.f) ||
                 (vv[it].z != 0.f) || (vv[it].w != 0.f);
            float d = q4[it].x * kv[it].x + q4[it].y * kv[it].y +
                      q4[it].z * kv[it].z + q4[it].w * kv[it].w;
            d += __shfl_xor(d, 1);
            d += __shfl_xor(d, 2);
            d += __shfl_xor(d, 4);
            d += __shfl_xor(d, 8);
            sc[it] = d;   // score for head it*4 + (ld>>4)
        }
        if (__ballot(nz) != 0ull) {
#pragma unroll
            for (int it = 0; it < 4; ++it) {
                float mo = m4[it];
                float mn = fmaxf(mo, sc[it]);
                float sl = __expf(mo - mn);
                float w  = __expf(sc[it] - mn);
                l4[it] = l4[it] * sl + w;
                a4[it].x = a4[it].x * sl + w * vv[it].x;
                a4[it].y = a4[it].y * sl + w * vv[it].y;
                a4[it].z = a4[it].z * sl + w * vv[it].z;
                a4[it].w = a4[it].w * sl + w * vv[it].w;
                m4[it] = mn;
            }
        }
    }
#pragma unroll
    for (int it = 0; it < 4; ++it) {
        int h = it * 4 + (ld >> 4);
        if ((ld & 15) == 0) {
            pm[wid * 16 + h] = m4[it];
            pl[wid * 16 + h] = l4[it];
        }
        *(float4*)(pacc + (size_t)wid * EDIM + it * 256 + ld * 4) = a4[it];
    }
}

// stage 1 reduce: grid (16 heads, 16 groups), block 64. R partials per group.
__global__ __launch_bounds__(64) void attn_red1(
    const float* __restrict__ pm, const float* __restrict__ pl,
    const float* __restrict__ pacc,
    float* __restrict__ m2, float* __restrict__ l2, float* __restrict__ acc2,
    int R) {
    int h = blockIdx.x, g = blockIdx.y, ld = threadIdx.x;
    int p0 = g * R;
    float lm = -1e30f;
#pragma unroll 8
    for (int i = 0; i < R; ++i) lm = fmaxf(lm, pm[(p0 + i) * 16 + h]);
    float l = 0.f, a = 0.f;
#pragma unroll 4
    for (int i = 0; i < R; ++i) {
        float w = __expf(pm[(p0 + i) * 16 + h] - lm);
        l += w * pl[(p0 + i) * 16 + h];
        a += w * pacc[(size_t)(p0 + i) * EDIM + h * 64 + ld];
    }
    if (ld == 0) { m2[g * 16 + h] = lm; l2[g * 16 + h] = l; }
    acc2[(size_t)g * EDIM + h * 64 + ld] = a;
}

// Wo GEMV with fused final attention reduce.
// grid (4, 16), block 256. blockIdx.y = 64-row slice = one head.
__global__ __launch_bounds__(256) void gemv_wo(
    const float* __restrict__ Wo,
    const float* __restrict__ m2, const float* __restrict__ l2,
    const float* __restrict__ acc2, float* __restrict__ part) {
    __shared__ float vals[64];
    int by = blockIdx.y;   // head index
    int t = threadIdx.x;
    float M = -1e30f;
#pragma unroll
    for (int g = 0; g < 16; ++g) M = fmaxf(M, m2[g * 16 + by]);
    float L = 0.f;
#pragma unroll
    for (int g = 0; g < 16; ++g) L += __expf(m2[g * 16 + by] - M) * l2[g * 16 + by];
    if (t < 64) {
        float a = 0.f;
#pragma unroll
        for (int g = 0; g < 16; ++g)
            a += __expf(m2[g * 16 + by] - M) * acc2[(size_t)g * EDIM + by * 64 + t];
        vals[t] = a / L;
    }
    __syncthreads();
    int col = blockIdx.x * 256 + t;
    float acc = 0.f;
#pragma unroll 8
    for (int r = 0; r < 64; ++r)
        acc = fmaf(vals[r], Wo[(size_t)(by * 64 + r) * EDIM + col], acc);
    part[(size_t)by * EDIM + col] = acc;
}

// generic GEMV partial: grid (4,16), block 256
__global__ __launch_bounds__(256) void gemv_partial(
    const float* __restrict__ W, const float* __restrict__ xin,
    float* __restrict__ part) {
    int col = blockIdx.x * 256 + threadIdx.x;
    int r0 = blockIdx.y * 64;
    float acc = 0.f;
#pragma unroll 8
    for (int r = 0; r < 64; ++r)
        acc = fmaf(xin[r0 + r], W[(size_t)(r0 + r) * EDIM + col], acc);
    part[(size_t)blockIdx.y * EDIM + col] = acc;
}

// W2 GEMV with fused (bias + sum-partials + ReLU) prologue for its row slice.
__global__ __launch_bounds__(256) void gemv_w2(
    const float* __restrict__ W2, const float* __restrict__ gp2,
    const float* __restrict__ b1, float* __restrict__ part) {
    __shared__ float vals[64];
    int by = blockIdx.y;
    int t = threadIdx.x;
    if (t < 64) {
        int r = by * 64 + t;
        float v = b1[r];
#pragma unroll
        for (int sl = 0; sl < 16; ++sl) v += gp2[(size_t)sl * EDIM + r];
        vals[t] = fmaxf(v, 0.f);
    }
    __syncthreads();
    int col = blockIdx.x * 256 + t;
    float acc = 0.f;
#pragma unroll 8
    for (int r = 0; r < 64; ++r)
        acc = fmaf(vals[r], W2[(size_t)(by * 64 + r) * EDIM + col], acc);
    part[(size_t)by * EDIM + col] = acc;
}

// 1 block 1024: r = resid + bias + sum partials; out = LN(r)*g + b
__global__ __launch_bounds__(1024) void combine_ln(
    const float* __restrict__ part, const float* __restrict__ bias,
    const float* __restrict__ resid, const float* __restrict__ g,
    const float* __restrict__ b, float* __restrict__ out) {
    __shared__ float lds[32];
    int t = threadIdx.x;
    float v = bias[t];
#pragma unroll
    for (int sl = 0; sl < 16; ++sl) v += part[(size_t)sl * EDIM + t];
    float r = resid[t] + v;
    float mean = blockSum1024(r, lds) * (1.f / 1024.f);
    float d = r - mean;
    float var = blockSum1024(d * d, lds) * (1.f / 1024.f);
    out[t] = d * rsqrtf(var + 1e-6f) * g[t] + b[t];
}

// ---------------- launch ----------------
extern "C" void kernel_launch(void* const* d_in, const int* in_sizes, int n_in,
                              void* d_out, int out_size, void* d_ws, size_t ws_size,
                              hipStream_t stream) {
    const float* x     = (const float*)d_in[0];
    const float* cache = (const float*)d_in[1];
    const float* Wv    = (const float*)d_in[2];
    const float* bv    = (const float*)d_in[3];
    const float* Wq    = (const float*)d_in[4];
    const float* bq    = (const float*)d_in[5];
    const float* Wk    = (const float*)d_in[6];
    const float* bk    = (const float*)d_in[7];
    const float* Wo    = (const float*)d_in[8];
    const float* bo    = (const float*)d_in[9];
    const float* W1    = (const float*)d_in[10];
    const float* b1    = (const float*)d_in[11];
    const float* W2    = (const float*)d_in[12];
    const float* b2    = (const float*)d_in[13];
    const float* ln1s  = (const float*)d_in[14];
    const float* ln1b  = (const float*)d_in[15];
    const float* ln2s  = (const float*)d_in[16];
    const float* ln2b  = (const float*)d_in[17];

    float* out = (float*)d_out;
    float* nv = out + 1024;
    float* nk = out + 1024 + (size_t)SLEN * EDIM;

    size_t ws_floats = ws_size / 4;
    int NW = 2048;
    if (ws_floats < (size_t)119296 + (size_t)2048 * 1056) NW = 1024;
    int R = NW / 16;

    float* w      = (float*)d_ws;
    float* qs     = w;                          // 1024
    float* ki     = qs + 1024;                  // 1024
    float* vi     = ki + 1024;                  // 1024
    float* qkvp   = vi + 1024;                  // 48*1024
    float* pm     = qkvp + 48 * 1024;           // NW*16
    float* pl     = pm + (size_t)NW * 16;       // NW*16
    float* pacc   = pl + (size_t)NW * 16;       // NW*1024
    float* m2     = pacc + (size_t)NW * 1024;   // 256
    float* l2     = m2 + 256;                   // 256
    float* acc2   = l2 + 256;                   // 16*1024
    float* h1     = acc2 + 16 * 1024;           // 1024
    float* gp1    = h1 + 1024;                  // 16*1024
    float* gp2    = gp1 + 16 * 1024;            // 16*1024
    float* gp3    = gp2 + 16 * 1024;            // 16*1024

    qkv_partial<<<dim3(12, 16), 256, 0, stream>>>(Wq, Wk, Wv, x, qkvp);
    qkv_combine<<<3, 1024, 0, stream>>>(qkvp, bq, bk, bv, qs, ki, vi);
    if (NW == 2048)
        attn_main<4><<<512, 256, 0, stream>>>(cache, qs, ki, vi, nv, nk, pm, pl, pacc);
    else
        attn_main<8><<<256, 256, 0, stream>>>(cache, qs, ki, vi, nv, nk, pm, pl, pacc);
    attn_red1<<<dim3(16, 16), 64, 0, stream>>>(pm, pl, pacc, m2, l2, acc2, R);
    gemv_wo<<<dim3(4, 16), 256, 0, stream>>>(Wo, m2, l2, acc2, gp1);
    combine_ln<<<1, 1024, 0, stream>>>(gp1, bo, x, ln1s, ln1b, h1);
    gemv_partial<<<dim3(4, 16), 256, 0, stream>>>(W1, h1, gp2);
    gemv_w2<<<dim3(4, 16), 256, 0, stream>>>(W2, gp2, b1, gp3);
    combine_ln<<<1, 1024, 0, stream>>>(gp3, b2, h1, ln2s, ln2b, out);
}